// Round 1
// baseline (603.274 us; speedup 1.0000x reference)
//
#include <hip/hip_runtime.h>
#include <cstddef>
#include <cstdint>

#define NEGV -1e30f

constexpr int B_    = 32;
constexpr int TXT   = 256;
constexpr int MEL   = 2048;
constexpr int NMEL  = 80;

// ---------------------------------------------------------------------------
// Kernel P: per (b,j): iv[c]=exp(-logvar), m2[c]=2*mu*iv, s = sum(mu^2*iv + logvar)
// Writes IV/M2 transposed to [b][c][j] for coalesced LDS staging in kernel 1.
// ---------------------------------------------------------------------------
__global__ __launch_bounds__(256) void precompute_kernel(
    const float* __restrict__ mu_logvar,
    float* __restrict__ IV, float* __restrict__ M2, float* __restrict__ S)
{
    const int b = blockIdx.x;
    const int j = threadIdx.x;
    const float* row = mu_logvar + (size_t)(b * TXT + j) * (2 * NMEL);
    float s = 0.f;
    for (int c = 0; c < NMEL; ++c) {
        float mu = row[c];
        float lv = row[NMEL + c];
        float iv = expf(-lv);
        IV[(b * NMEL + c) * TXT + j] = iv;
        M2[(b * NMEL + c) * TXT + j] = 2.0f * mu * iv;
        s += mu * mu * iv + lv;
    }
    S[b * TXT + j] = s;
}

// ---------------------------------------------------------------------------
// Kernel 1: log_prob. Tile 64 j x 128 t per block (256 threads).
// Thread (tx,ty): tx in [0,16) (t), ty in [0,16) (j); computes 4 j x 8 t.
// Dual-writes: out[b][j][t] (at d_out+1) and (optionally) lpT[b][t][j] in ws.
// ---------------------------------------------------------------------------
__global__ __launch_bounds__(256) void logprob_kernel(
    const float* __restrict__ mel,
    const float* __restrict__ IV, const float* __restrict__ M2,
    const float* __restrict__ S,
    float* __restrict__ out1,          // d_out + 1 (log_prob region)
    float* __restrict__ lpT,           // ws transposed copy [b][t][j]
    int write_lpT)
{
    const int tt0 = blockIdx.x * 128;
    const int j0  = blockIdx.y * 64;
    const int b   = blockIdx.z;
    const int tx  = threadIdx.x & 15;
    const int ty  = threadIdx.x >> 4;

    __shared__ float sIV[NMEL][64];
    __shared__ float sM2[NMEL][64];

    for (int idx = threadIdx.x; idx < NMEL * 64; idx += 256) {
        int c  = idx >> 6;
        int jj = idx & 63;
        sIV[c][jj] = IV[(b * NMEL + c) * TXT + j0 + jj];
        sM2[c][jj] = M2[(b * NMEL + c) * TXT + j0 + jj];
    }
    __syncthreads();

    float acc[4][8];
#pragma unroll
    for (int a = 0; a < 4; ++a)
#pragma unroll
        for (int d = 0; d < 8; ++d) acc[a][d] = 0.f;

    const float* melb = mel + (size_t)b * NMEL * MEL + tt0 + tx;

#pragma unroll 2
    for (int c = 0; c < NMEL; ++c) {
        float x[8];
#pragma unroll
        for (int d = 0; d < 8; ++d) x[d] = melb[(size_t)c * MEL + 16 * d];
        float4 iv = *(const float4*)&sIV[c][ty * 4];
        float4 m2 = *(const float4*)&sM2[c][ty * 4];
        float ivr[4] = {iv.x, iv.y, iv.z, iv.w};
        float m2r[4] = {m2.x, m2.y, m2.z, m2.w};
#pragma unroll
        for (int a = 0; a < 4; ++a) {
#pragma unroll
            for (int d = 0; d < 8; ++d) {
                // contribution = iv*x^2 - m2*x = x*(iv*x - m2)
                float tmp = fmaf(ivr[a], x[d], -m2r[a]);
                acc[a][d] = fmaf(tmp, x[d], acc[a][d]);
            }
        }
    }

    const float c0 = -0.5f / (float)NMEL;
    float4 sj = *(const float4*)&S[b * TXT + j0 + ty * 4];
    float sjr[4] = {sj.x, sj.y, sj.z, sj.w};

#pragma unroll
    for (int a = 0; a < 4; ++a) {
        const int j = j0 + ty * 4 + a;
        float* ob = out1 + (size_t)(b * TXT + j) * MEL + tt0 + tx;
#pragma unroll
        for (int d = 0; d < 8; ++d) {
            float v = c0 * (acc[a][d] + sjr[a]);
            ob[16 * d] = v;
            if (write_lpT) {
                lpT[((size_t)b * MEL + tt0 + tx + 16 * d) * TXT + j] = v;
            }
        }
    }
}

// ---------------------------------------------------------------------------
// DP kernel: one block per batch b, 256 threads (thread = j), 4 waves.
// Serial over t; logaddexp chain; cross-wave boundary via LDS double buffer.
// TRANS: read lpT[b][t][j] (coalesced). else read lp[b][j][t] (slow fallback).
// ---------------------------------------------------------------------------
template <bool TRANS>
__global__ __launch_bounds__(256) void dp_kernel(
    const float* __restrict__ lp,
    const int* __restrict__ tlen, const int* __restrict__ mlen,
    float* __restrict__ alpha)
{
    const int b    = blockIdx.x;
    const int j    = threadIdx.x;
    const int lane = j & 63;
    const int w    = j >> 6;

    const int tl   = tlen[b];
    const int ml   = mlen[b];
    const int tmax = ml - 1;
    const int jt   = tl - 1;
    const float inv_ml = 1.0f / (float)ml;

    __shared__ float bnd[2][4];
    if (threadIdx.x < 8) bnd[threadIdx.x >> 2][threadIdx.x & 3] = NEGV;
    __syncthreads();

    auto LOAD = [&](int t) -> float {
        return TRANS ? lp[((size_t)b * MEL + t) * TXT + j]
                     : lp[((size_t)(b * TXT + j)) * MEL + t];
    };

    float cur = (j == 0) ? LOAD(0) : NEGV;

    if (tmax == 0) {
        if (j == jt) alpha[b] = cur * inv_ml;
        return;
    }

    int p = 0;

#define DP_STEP(TT, LPC)                                                      \
    {                                                                         \
        float sh = __shfl_up(cur, 1);                                         \
        if (lane == 0) sh = (w > 0) ? bnd[p][w - 1] : NEGV;                   \
        float mx = fmaxf(cur, sh);                                            \
        float dd = fminf(cur, sh) - mx;                                       \
        float nv = mx + __logf(1.0f + __expf(dd)) + (LPC);                    \
        if (lane == 63) bnd[p ^ 1][w] = nv;                                   \
        if ((TT) == tmax && j == jt) alpha[b] = nv * inv_ml;                  \
        cur = nv;                                                             \
        __syncthreads();                                                      \
        p ^= 1;                                                               \
    }

    float buf[8];
#pragma unroll
    for (int i = 0; i < 8; ++i) buf[i] = LOAD(min(1 + i, tmax));

    int t = 1;
    for (; t + 7 <= tmax; t += 8) {
#pragma unroll
        for (int s = 0; s < 8; ++s) {
            float lpc = buf[s];
            buf[s] = LOAD(min(t + s + 8, tmax));
            DP_STEP(t + s, lpc);
        }
    }
#pragma unroll
    for (int s = 0; s < 8; ++s) {
        if (t + s <= tmax) {
            DP_STEP(t + s, buf[s]);
        }
    }
#undef DP_STEP
}

// ---------------------------------------------------------------------------
// Reduce: loss = -mean_b(alpha[b])
// ---------------------------------------------------------------------------
__global__ void reduce_kernel(const float* __restrict__ alpha, float* __restrict__ out)
{
    const int tid = threadIdx.x;
    float v = (tid < B_) ? alpha[tid] : 0.f;
#pragma unroll
    for (int m = 16; m >= 1; m >>= 1) v += __shfl_xor(v, m);
    if (tid == 0) out[0] = -v / (float)B_;
}

// ---------------------------------------------------------------------------
extern "C" void kernel_launch(void* const* d_in, const int* in_sizes, int n_in,
                              void* d_out, int out_size, void* d_ws, size_t ws_size,
                              hipStream_t stream)
{
    const float* mu_logvar = (const float*)d_in[0];
    const float* melspec   = (const float*)d_in[1];
    const int*   tlen      = (const int*)d_in[2];
    const int*   mlen      = (const int*)d_in[3];
    float* out = (float*)d_out;
    float* ws  = (float*)d_ws;

    // ws layout (floats)
    const size_t IV_OFF    = 0;                        // 32*80*256 = 655360
    const size_t M2_OFF    = 655360;                   // 655360
    const size_t S_OFF     = 1310720;                  // 8192
    const size_t ALPHA_OFF = 1318912;                  // 32
    const size_t LPT_OFF   = 1318944;                  // 16,777,216 (67MB, optional)
    const size_t LPT_ELEMS = (size_t)B_ * MEL * TXT;

    float* IV    = ws + IV_OFF;
    float* M2    = ws + M2_OFF;
    float* S     = ws + S_OFF;
    float* alpha = ws + ALPHA_OFF;
    float* lpT   = ws + LPT_OFF;

    const bool use_lpT = ws_size >= (LPT_OFF + LPT_ELEMS) * sizeof(float);

    precompute_kernel<<<dim3(B_), dim3(256), 0, stream>>>(mu_logvar, IV, M2, S);

    logprob_kernel<<<dim3(MEL / 128, TXT / 64, B_), dim3(256), 0, stream>>>(
        melspec, IV, M2, S, out + 1, lpT, use_lpT ? 1 : 0);

    if (use_lpT) {
        dp_kernel<true><<<dim3(B_), dim3(256), 0, stream>>>(lpT, tlen, mlen, alpha);
    } else {
        dp_kernel<false><<<dim3(B_), dim3(256), 0, stream>>>(out + 1, tlen, mlen, alpha);
    }

    reduce_kernel<<<dim3(1), dim3(64), 0, stream>>>(alpha, out);
}